// Round 1
// baseline (38.101 us; speedup 1.0000x reference)
//
#include <hip/hip_runtime.h>

#define TWO_PI 6.2831853071795864769f

// ---------------------------------------------------------------------------
// ws layout (bytes):
//   C       : [6*256*256] f32   @ 0          (1572864 B)  dense base mem
//   W       : [6*256*256] int   @ 1572864    (1572864 B)  winner map (last-wins)
//   cnt     : [6] int           @ 3145728    (pad to 256)
//   list_de : [6][2048] int     @ 3145984    (49152 B)    packed (d<<16)|e
//   list_v  : [3][6][2048] f32  @ 3195136    (147456 B)   per-stage scattered vals
// total ~3.2 MB
// ---------------------------------------------------------------------------

__global__ __launch_bounds__(256) void build_c_kernel(
    const float* __restrict__ P1, const float* __restrict__ P3,
    float* __restrict__ C, int* __restrict__ W)
{
    int i = blockIdx.x * 256 + threadIdx.x;   // 1536 blocks * 256 = 393216
    C[i] = fmaf(P3[i], 0.975f, P1[i]);
    W[i] = -1;
}

// Single block (single CU): atomicMax winners, then __syncthreads orders the
// readback (same L1, no cross-CU staleness possible).
__global__ __launch_bounds__(1024) void prep_kernel(
    const int* __restrict__ p5, const int* __restrict__ p6,
    const int* __restrict__ p7, const int* __restrict__ p8,
    const float* __restrict__ t4, const float* __restrict__ t11,
    const float* __restrict__ t14, const float* __restrict__ P3,
    float* __restrict__ C, int* __restrict__ W,
    int* __restrict__ cnt, int* __restrict__ list_de,
    float* __restrict__ list_v, int K)
{
    __shared__ int scnt[6];
    int tid = threadIdx.x;
    if (tid < 6) scnt[tid] = 0;
    __syncthreads();
    for (int k = tid; k < K; k += 1024) {
        int b = p5[k], d = p7[k], e = p8[k];
        int pos = (b * 256 + d) * 256 + e;
        atomicMax(&W[pos], k);
        // zero out P1 contribution at ALL scattered slots (winner or not):
        // every duplicate writes the identical value -> benign race
        C[pos] = 0.975f * P3[pos];
    }
    __syncthreads();
    for (int k = tid; k < K; k += 1024) {
        int b = p5[k], d = p7[k], e = p8[k];
        int pos = (b * 256 + d) * 256 + e;
        if (W[pos] == k) {                       // last occurrence wins (np semantics)
            int idx = atomicAdd(&scnt[b], 1);
            int c = p6[k];
            list_de[b * 2048 + idx] = (d << 16) | e;
            list_v[(0 * 6 + b) * 2048 + idx] = t4 [b * 256 + c];
            list_v[(1 * 6 + b) * 2048 + idx] = t11[b * 256 + c];
            list_v[(2 * 6 + b) * 2048 + idx] = t14[b * 256 + c];
        }
    }
    __syncthreads();
    if (tid < 6) cnt[tid] = scnt[tid];
}

// One block per (h,b) chain. 1024 threads = (quarter q 0..3) x (e 0..255).
// Each stage: dense row-vec x C[b] (d split across quarters), LDS reduce,
// sparse scatter-corrections via LDS atomics, modulation, next stage.
__global__ __launch_bounds__(1024) void chain_kernel(
    const float* __restrict__ C, const float* __restrict__ P2,
    const int* __restrict__ cnt, const int* __restrict__ list_de,
    const float* __restrict__ list_v,
    const float* __restrict__ f1, const float* __restrict__ ph1,
    const float* __restrict__ f2, const float* __restrict__ ph2,
    const float* __restrict__ f3, const float* __restrict__ ph3,
    float* __restrict__ out)
{
    int blk = blockIdx.x;
    int h = blk / 6, b = blk - h * 6;
    int tid = threadIdx.x;
    int e = tid & 255;
    int q = tid >> 8;
    __shared__ float v[256];
    __shared__ float pv[4][256];
    const float* Cb = C + b * 65536;
    if (q == 0) v[e] = P2[(h * 6 + b) * 256 + e];
    float frs[3], phs[3];
    frs[0] = f1[0];  frs[1] = f2[0];  frs[2] = f3[0];
    phs[0] = ph1[0]; phs[1] = ph2[0]; phs[2] = ph3[0];
    int nb = cnt[b];
    __syncthreads();

    for (int s = 0; s < 3; ++s) {
        const float* Cq = Cb + (q * 64) * 256 + e;
        const int dbase = q * 64;
        float a0 = 0.f, a1 = 0.f, a2 = 0.f, a3 = 0.f;
        #pragma unroll 4
        for (int d = 0; d < 64; d += 4) {
            a0 = fmaf(v[dbase + d    ], Cq[(d    ) * 256], a0);
            a1 = fmaf(v[dbase + d + 1], Cq[(d + 1) * 256], a1);
            a2 = fmaf(v[dbase + d + 2], Cq[(d + 2) * 256], a2);
            a3 = fmaf(v[dbase + d + 3], Cq[(d + 3) * 256], a3);
        }
        pv[q][e] = (a0 + a1) + (a2 + a3);
        __syncthreads();
        if (q == 0) pv[0][e] = (pv[0][e] + pv[1][e]) + (pv[2][e] + pv[3][e]);
        __syncthreads();
        // sparse corrections: att[.,b,e] += v[d] * val_s  at winner entries
        const float* lv = list_v + (s * 6 + b) * 2048;
        for (int i = tid; i < nb; i += 1024) {
            int de = list_de[b * 2048 + i];
            atomicAdd(&pv[0][de & 0xffff], v[de >> 16] * lv[i]);
        }
        __syncthreads();
        if (q == 0) {
            float t = (float)e;
            float sn = sinf(t * TWO_PI * frs[s] + phs[s]);
            float m = sn * sn * 0.1f + 0.95f;
            float x = pv[0][e];
            v[e] = (s == 1) ? x * m : x / m;   // stage1: /m1, stage2: *m2, stage3: /m3
        }
        __syncthreads();
    }
    if (q == 0) out[(h * 6 + b) * 256 + e] = v[e];
}

extern "C" void kernel_launch(void* const* d_in, const int* in_sizes, int n_in,
                              void* d_out, int out_size, void* d_ws, size_t ws_size,
                              hipStream_t stream)
{
    (void)n_in; (void)out_size; (void)ws_size;
    const float* P1  = (const float*)d_in[0];
    const float* P2  = (const float*)d_in[1];
    const float* P3  = (const float*)d_in[2];
    const float* T4  = (const float*)d_in[3];
    const int*   p5  = (const int*)d_in[4];
    const int*   p6  = (const int*)d_in[5];
    const int*   p7  = (const int*)d_in[6];
    const int*   p8  = (const int*)d_in[7];
    const float* f1  = (const float*)d_in[8];
    const float* ph1 = (const float*)d_in[9];
    const float* T11 = (const float*)d_in[10];
    const float* f2  = (const float*)d_in[11];
    const float* ph2 = (const float*)d_in[12];
    const float* T14 = (const float*)d_in[13];
    const float* f3  = (const float*)d_in[14];
    const float* ph3 = (const float*)d_in[15];
    float* out = (float*)d_out;
    int K = in_sizes[4];

    char* ws = (char*)d_ws;
    float* C       = (float*)(ws);
    int*   W       = (int*)  (ws + 1572864);
    int*   cnt     = (int*)  (ws + 3145728);
    int*   list_de = (int*)  (ws + 3145984);
    float* list_v  = (float*)(ws + 3195136);

    hipLaunchKernelGGL(build_c_kernel, dim3(1536), dim3(256), 0, stream,
                       P1, P3, C, W);
    hipLaunchKernelGGL(prep_kernel, dim3(1), dim3(1024), 0, stream,
                       p5, p6, p7, p8, T4, T11, T14, P3, C, W,
                       cnt, list_de, list_v, K);
    hipLaunchKernelGGL(chain_kernel, dim3(72), dim3(1024), 0, stream,
                       C, P2, cnt, list_de, list_v,
                       f1, ph1, f2, ph2, f3, ph3, out);
}